// Round 10
// baseline (114.575 us; speedup 1.0000x reference)
//
#include <hip/hip_runtime.h>
#include <stdint.h>

#define BB 16
#define SS 10
#define CLSN 4
#define FGN 3
#define HH 192
#define WW 192
#define NPIX (HH * WW)    // 36864
#define WPR 3             // u64 words per row
#define NWORDS (HH * WPR) // 576
#define NPAIR (BB * SS)   // 160
#define NTASK (NPAIR * FGN) // 480
#define NT 512
#define NW 8
#define MAXRUNS 8192      // mean ~6924, sigma ~76

typedef unsigned long long u64;
typedef unsigned short u16;
typedef unsigned int u32;

// Dynamic LDS layout (bytes):
//   fgw    : 0     .. 4608   (576 u64)
//   stm    : 4608  .. 9216   (576 u64 run-start masks)
//   cmp    : 9216  .. 13824  (576 u64)
//   parent : 13824 .. 46592  (8192 u32)
//   roff   : 46592 .. 47364  (193 int)
//   wkey   : 47368 .. 47400  (8 u32)
//   wsum   : 47400 .. 47464  (8 double)
//   seedSh : 47464 ; seedRoot: 47468 ; cntSh: 47472
//   wlist  : 47476 .. 48628  (576 short)
#define SMEM_BYTES 48640

// full adder: s = a^b^c, cy = majority(a,b,c)
#define FAD(a, b, c, s, cy)            \
    do {                               \
        u64 t_ = (a) ^ (b);            \
        (s) = t_ ^ (c);                \
        (cy) = ((a) & (b)) | (t_ & (c)); \
    } while (0)

// bit-sliced 3x3 ones-conv of bitboard `bd` at word k: 4 count bit-planes + center
__device__ __forceinline__ void plane9(const u64* bd, int k,
                                       u64& P0, u64& P1, u64& P2, u64& P3, u64& mid)
{
    const int r = k / WPR;
    const int wc = k - r * WPR;
    u64 rows[3][3];
#pragma unroll
    for (int di = 0; di < 3; ++di) {
        int rr = r + di - 1;
#pragma unroll
        for (int dj = 0; dj < 3; ++dj) {
            int ww = wc + dj - 1;
            rows[di][dj] = (rr >= 0 && rr < HH && ww >= 0 && ww < WPR)
                           ? bd[rr * WPR + ww] : 0ULL;
        }
    }
    mid = rows[1][1];
    u64 in[9];
#pragma unroll
    for (int i = 0; i < 3; ++i) {
        u64 m = rows[i][1], lf = rows[i][0], rg = rows[i][2];
        in[3 * i + 0] = m;
        in[3 * i + 1] = (m << 1) | (lf >> 63);
        in[3 * i + 2] = (m >> 1) | (rg << 63);
    }
    u64 s0a, c0a, s0b, c0b, s0c, c0c, c0d, s1a, c1a, c1b;
    FAD(in[0], in[1], in[2], s0a, c0a);
    FAD(in[3], in[4], in[5], s0b, c0b);
    FAD(in[6], in[7], in[8], s0c, c0c);
    FAD(s0a, s0b, s0c, P0, c0d);
    FAD(c0a, c0b, c0c, s1a, c1a);
    P1 = s1a ^ c0d;
    c1b = s1a & c0d;
    P2 = c1a ^ c1b;
    P3 = c1a & c1b;
}

// number of start bits at position <= pos within a row's 3-word start mask
__device__ __forceinline__ int rankLE(const u64* st, int pos)
{
    const int w = pos >> 6, b = pos & 63;
    int cnt = 0;
    if (w > 0) cnt += (int)__popcll(st[0]);
    if (w > 1) cnt += (int)__popcll(st[1]);
    const u64 mm = st[w] & ((b == 63) ? ~0ULL : ((2ULL << b) - 1ULL));
    cnt += (int)__popcll(mm);
    return cnt;
}

// position of last fg bit in window [lo,hi] of a 3-word row, or -1
__device__ __forceinline__ int lastFg(const u64* fr, int lo, int hi)
{
    const int wl = lo >> 6, wh = hi >> 6;
    for (int w = wh; w >= wl; --w) {
        u64 mm = fr[w];
        if (w == wh) { const int b = hi & 63; mm &= (b == 63) ? ~0ULL : ((2ULL << b) - 1ULL); }
        if (w == wl) mm &= (~0ULL << (lo & 63));
        if (mm) return (w << 6) + 63 - (int)__clzll(mm);
    }
    return -1;
}

// ECL-CC find with path halving (parents only decrease -> race-safe)
__device__ __forceinline__ u32 repr(u32 v, u32* P)
{
    u32 cur = ((volatile u32*)P)[v];
    if (cur != v) {
        u32 prev = v, next;
        while (cur > (next = ((volatile u32*)P)[cur])) {
            ((volatile u32*)P)[prev] = next;
            prev = cur; cur = next;
        }
    }
    return cur;
}

__device__ __forceinline__ void unite(u32 a, u32 b, u32* P)
{
    u32 x = repr(a, P), y = repr(b, P);
    while (x != y) {
        if (x < y) { u32 t = x; x = y; y = t; }   // x > y: hook x -> y
        u32 old = atomicCAS(&P[x], x, y);
        if (old == x) return;
        x = repr(old, P);
        y = repr(y, P);
    }
}

__global__ __launch_bounds__(NT) void cc_fused(
    const float* __restrict__ preds,
    const int* __restrict__ samples,
    double* __restrict__ acc)
{
    extern __shared__ char smem[];
    u64* fgw      = (u64*)(smem);
    u64* stm      = (u64*)(smem + 4608);
    u64* cmp      = (u64*)(smem + 9216);
    u32* parent   = (u32*)(smem + 13824);
    int* roff     = (int*)(smem + 46592);
    u32* wkey     = (u32*)(smem + 47368);
    double* wsum  = (double*)(smem + 47400);
    u32* seedShP  = (u32*)(smem + 47464);
    u32* seedRtP  = (u32*)(smem + 47468);
    int* cntShP   = (int*)(smem + 47472);
    short* wlist  = (short*)(smem + 47476);

    const int blk = blockIdx.x;
    const int c = 1 + blk / NPAIR;
    const int pair = blk % NPAIR;
    const int b = pair / SS;

    const int tid  = threadIdx.x;
    const int lane = tid & 63;
    const int wv   = tid >> 6;

    const int* __restrict__ smp  = samples + (size_t)pair * NPIX;
    const float* __restrict__ pp = preds + ((size_t)b * CLSN + c) * NPIX;

    if (tid == 0) *cntShP = 0;

    float facc = 0.0f;

    // ---- Phase A: int4/float4 loads; 16-px mask nibble -> LDS u16 alias of fgw.
    // Fused dense term: -sum_{v==c} log(p + 1e-8).
    {
        u16* nib = (u16*)fgw;
        for (int u = tid; u < NPIX / 16; u += NT) {
            const int px = u << 4;
            const int4 v0 = *(const int4*)(smp + px);
            const int4 v1 = *(const int4*)(smp + px + 4);
            const int4 v2 = *(const int4*)(smp + px + 8);
            const int4 v3 = *(const int4*)(smp + px + 12);
            const float4 q0 = *(const float4*)(pp + px);
            const float4 q1 = *(const float4*)(pp + px + 4);
            const float4 q2 = *(const float4*)(pp + px + 8);
            const float4 q3 = *(const float4*)(pp + px + 12);
            unsigned m = 0u;
#define ACC1(vv, qq, sh)                                              \
            {                                                          \
                const bool hit_ = ((vv) == c);                         \
                m |= ((unsigned)hit_) << (sh);                         \
                facc -= hit_ ? __logf((qq) + 1e-8f) : 0.0f;            \
            }
            ACC1(v0.x, q0.x, 0)  ACC1(v0.y, q0.y, 1)
            ACC1(v0.z, q0.z, 2)  ACC1(v0.w, q0.w, 3)
            ACC1(v1.x, q1.x, 4)  ACC1(v1.y, q1.y, 5)
            ACC1(v1.z, q1.z, 6)  ACC1(v1.w, q1.w, 7)
            ACC1(v2.x, q2.x, 8)  ACC1(v2.y, q2.y, 9)
            ACC1(v2.z, q2.z, 10) ACC1(v2.w, q2.w, 11)
            ACC1(v3.x, q3.x, 12) ACC1(v3.y, q3.y, 13)
            ACC1(v3.z, q3.z, 14) ACC1(v3.w, q3.w, 15)
#undef ACC1
            nib[u] = (u16)m;
        }
    }
    __syncthreads();

    // ---- Phase B: argmax seed + start masks + per-row run counts + parent init ----
    {
        unsigned bestkey = 0u;
        for (int k = tid; k < NWORDS; k += NT) {
            u64 P0, P1, P2, P3, mid;
            plane9(fgw, k, P0, P1, P2, P3, mid);
            if (mid) {
                u64 cand = mid, t;
                unsigned v = 0;
                t = cand & P3; if (t) { cand = t; v |= 8u; }
                t = cand & P2; if (t) { cand = t; v |= 4u; }
                t = cand & P1; if (t) { cand = t; v |= 2u; }
                t = cand & P0; if (t) { cand = t; v |= 1u; }
                unsigned pix = ((unsigned)k << 6) + (unsigned)(__ffsll(cand) - 1);
                unsigned key = (v << 16) | (36863u - pix);
                if (key > bestkey) bestkey = key;
            }
        }
#pragma unroll
        for (int off = 32; off > 0; off >>= 1) {
            unsigned o = (unsigned)__shfl_xor((int)bestkey, off, 64);
            if (o > bestkey) bestkey = o;
        }
        if (lane == 0) wkey[wv] = bestkey;

        for (int r = tid; r < HH; r += NT) {
            const u64* fr = fgw + r * WPR;
            const u64 s0 = fr[0] & ~(fr[0] << 1);
            const u64 s1 = fr[1] & ~((fr[1] << 1) | (fr[0] >> 63));
            const u64 s2 = fr[2] & ~((fr[2] << 1) | (fr[1] >> 63));
            stm[r * WPR + 0] = s0;
            stm[r * WPR + 1] = s1;
            stm[r * WPR + 2] = s2;
            roff[r] = (int)__popcll(s0) + (int)__popcll(s1) + (int)__popcll(s2);
        }
        for (int g = tid; g < MAXRUNS; g += NT) parent[g] = (u32)g;
    }
    __syncthreads();

    // seed reduce + exclusive scan of per-row counts (wave 0; lane owns 3 rows)
    if (tid == 0) {
        unsigned kk = 0u;
#pragma unroll
        for (int i = 0; i < NW; ++i)
            if (wkey[i] > kk) kk = wkey[i];
        *seedShP = 36863u - (kk & 0xFFFFu);
    }
    if (wv == 0) {
        const int r0 = 3 * lane;
        const int c0 = roff[r0], c1 = roff[r0 + 1], c2 = roff[r0 + 2];
        int x = c0 + c1 + c2;
        const int mysum = x;
#pragma unroll
        for (int off = 1; off < 64; off <<= 1) {
            int t = __shfl_up(x, off, 64);
            if (lane >= off) x += t;
        }
        const int excl = x - mysum;
        roff[r0] = excl;
        roff[r0 + 1] = excl + c0;
        roff[r0 + 2] = excl + c0 + c1;
        if (lane == 63) roff[HH] = x;
    }
    __syncthreads();

    const unsigned seed = *seedShP;
    const int srow = (int)(seed / WW);
    const int scol = (int)(seed % WW);

    // ---- C3: extract+link per (row,word) unit ----
    for (int u = tid; u < NWORDS; u += NT) {
        const int r = u / WPR, w = u - (u / WPR) * WPR;
        const u64 stw = stm[u];
        if (!stw) continue;
        const u64* fr = fgw + r * WPR;
        int kb = roff[r];
        if (w > 0) kb += (int)__popcll(stm[r * WPR]);
        if (w > 1) kb += (int)__popcll(stm[r * WPR + 1]);
        int j = 0;
        u64 m = stw;
        while (m) {
            const int sb = (int)__ffsll(m) - 1; m &= m - 1;
            const int s = (w << 6) + sb;
            int e = 191;
            int wj = w;
            u64 inv = ~fr[wj] & ((sb == 63) ? 0ULL : (~0ULL << (sb + 1)));
            while (!inv && wj < 2) { ++wj; inv = ~fr[wj]; }
            if (inv) e = (wj << 6) + (int)__ffsll(inv) - 2;
            const int g = kb + j; ++j;
            if (g >= MAXRUNS) break;
            const int lo = (s > 0) ? s - 1 : 0;
            const int hi = (e < 191) ? e + 1 : 191;
            if (r > 0) {
                const int q = lastFg(fgw + (r - 1) * WPR, lo, hi);
                if (q >= 0) {
                    const int p = roff[r - 1] + rankLE(stm + (r - 1) * WPR, q) - 1;
                    if (p < MAXRUNS) unite((u32)g, (u32)p, parent);
                }
            }
            if (r < HH - 1) {
                const int q = lastFg(fgw + (r + 1) * WPR, lo, hi);
                if (q >= 0) {
                    const int p = roff[r + 1] + rankLE(stm + (r + 1) * WPR, q) - 1;
                    if (p < MAXRUNS) unite((u32)g, (u32)p, parent);
                }
            }
        }
    }
    __syncthreads();

    // ---- C4: flatten ----
    {
        int total = roff[HH]; if (total > MAXRUNS) total = MAXRUNS;
        for (int g = tid; g < total; g += NT)
            parent[g] = repr((u32)g, parent);
    }
    __syncthreads();
    if (tid == 0) {
        u32 rt = 0xFFFFFFFFu;
        if ((fgw[srow * WPR + (scol >> 6)] >> (scol & 63)) & 1ULL) {
            const int g = roff[srow] + rankLE(stm + srow * WPR, scol) - 1;
            if (g < MAXRUNS) rt = parent[g];
        }
        *seedRtP = rt;
    }
    __syncthreads();

    // ---- C5: paint (each unit writes its cmp word once; no atomics) ----
    {
        const u32 root = *seedRtP;
        for (int u = tid; u < NWORDS; u += NT) {
            const int r = u / WPR, w = u - (u / WPR) * WPR;
            const u64 fw = fgw[u];
            u64 out = 0ULL;
            if (fw && root != 0xFFFFFFFFu) {
                u64 ls = fw & ~(fw << 1);  // local segment starts (incl. spill at bit0)
                while (ls) {
                    const int sb = (int)__ffsll(ls) - 1; ls &= ls - 1;
                    const int g = roff[r] + rankLE(stm + r * WPR, (w << 6) + sb) - 1;
                    const u64 inv = ~fw & ((sb == 63) ? 0ULL : (~0ULL << (sb + 1)));
                    const int eb = inv ? (int)__ffsll(inv) - 2 : 63;
                    if (g < MAXRUNS && parent[g] == root) {
                        const u64 mask = ((eb == 63) ? ~0ULL : ((2ULL << eb) - 1ULL))
                                       & (~0ULL << sb);
                        out |= mask;
                    }
                }
            }
            cmp[u] = out;
        }
    }
    __syncthreads();

    // ---- Phase D: compact nonempty comp words, split across waves,
    //      software-pipelined preds gather. facc += (cnt/9 + 1) * log(p).
    for (int k = tid; k < NWORDS; k += NT)
        if (cmp[k] != 0ULL) { int idx = atomicAdd(cntShP, 1); wlist[idx] = (short)k; }
    __syncthreads();
    {
        const int n = *cntShP;
        int i = wv;
        int kc = (i < n) ? (int)wlist[i] : -1;
        float pc = 0.0f;
        if (kc >= 0) pc = pp[(kc << 6) + lane];
        while (kc >= 0) {
            const int i2 = i + NW;
            const int k2 = (i2 < n) ? (int)wlist[i2] : -1;
            float p2 = 0.0f;
            if (k2 >= 0) p2 = pp[(k2 << 6) + lane];   // next load in flight
            u64 P0, P1, P2, P3, mid;
            plane9(cmp, kc, P0, P1, P2, P3, mid);
            if ((mid >> lane) & 1ULL) {
                int ct = (int)((P0 >> lane) & 1ULL)
                       | ((int)((P1 >> lane) & 1ULL) << 1)
                       | ((int)((P2 >> lane) & 1ULL) << 2)
                       | ((int)((P3 >> lane) & 1ULL) << 3);
                facc += ((float)ct * (1.0f / 9.0f) + 1.0f) * __logf(pc + 1e-8f);
            }
            i = i2; kc = k2; pc = p2;
        }
    }

    // ---- Reduce ----
#pragma unroll
    for (int off = 32; off > 0; off >>= 1)
        facc += __shfl_xor(facc, off, 64);
    if (lane == 0) wsum[wv] = (double)facc;
    __syncthreads();
    if (tid == 0) {
        double t = 0.0;
#pragma unroll
        for (int i = 0; i < NW; ++i) t += wsum[i];
        atomicAdd(acc, t);
    }
}

__global__ void finalize_kernel(const double* __restrict__ acc, float* __restrict__ out)
{
    if (threadIdx.x == 0 && blockIdx.x == 0)
        out[0] = (float)(-acc[0] / (double)((long long)BB * SS * NPIX));
}

extern "C" void kernel_launch(void* const* d_in, const int* in_sizes, int n_in,
                              void* d_out, int out_size, void* d_ws, size_t ws_size,
                              hipStream_t stream)
{
    const float* preds   = (const float*)d_in[0];
    const int*   samples = (const int*)d_in[1];
    double* acc = (double*)d_ws;

    hipMemsetAsync(acc, 0, sizeof(double), stream);
    hipLaunchKernelGGL(cc_fused, dim3(NTASK), dim3(NT), SMEM_BYTES, stream,
                       preds, samples, acc);
    hipLaunchKernelGGL(finalize_kernel, dim3(1), dim3(64), 0, stream,
                       acc, (float*)d_out);
}

// Round 11
// 58.233 us; speedup vs baseline: 1.9675x; 1.9675x over previous
//
#include <hip/hip_runtime.h>
#include <stdint.h>

#define BB 16
#define SS 10
#define CLSN 4
#define FGN 3
#define HH 192
#define WW 192
#define NPIX (HH * WW)    // 36864
#define WPR 3             // u64 words per row
#define NWORDS (HH * WPR) // 576
#define NPAIR (BB * SS)   // 160
#define NTASK (NPAIR * FGN) // 480
#define NT 256
#define NW 4

typedef unsigned long long u64;
typedef unsigned short u16;

// full adder: s = a^b^c, cy = majority(a,b,c)
#define FAD(a, b, c, s, cy)            \
    do {                               \
        u64 t_ = (a) ^ (b);            \
        (s) = t_ ^ (c);                \
        (cy) = ((a) & (b)) | (t_ & (c)); \
    } while (0)

// horizontal +/-1 smear of a 3-word row (192 bits)
#define SMEAR3(u0, u1, u2, s0, s1, s2)                          \
    do {                                                        \
        (s0) = (u0) | ((u0) << 1) | ((u0) >> 1) | ((u1) << 63); \
        (s1) = (u1) | ((u1) << 1) | ((u0) >> 63) | ((u1) >> 1) | ((u2) << 63); \
        (s2) = (u2) | ((u2) << 1) | ((u1) >> 63) | ((u2) >> 1); \
    } while (0)

// bit-sliced 3x3 ones-conv of bitboard `bd` at word k: 4 count bit-planes + center
__device__ __forceinline__ void plane9(const u64* bd, int k,
                                       u64& P0, u64& P1, u64& P2, u64& P3, u64& mid)
{
    const int r = k / WPR;
    const int wc = k - r * WPR;
    u64 rows[3][3];
#pragma unroll
    for (int di = 0; di < 3; ++di) {
        int rr = r + di - 1;
#pragma unroll
        for (int dj = 0; dj < 3; ++dj) {
            int ww = wc + dj - 1;
            rows[di][dj] = (rr >= 0 && rr < HH && ww >= 0 && ww < WPR)
                           ? bd[rr * WPR + ww] : 0ULL;
        }
    }
    mid = rows[1][1];
    u64 in[9];
#pragma unroll
    for (int i = 0; i < 3; ++i) {
        u64 m = rows[i][1], lf = rows[i][0], rg = rows[i][2];
        in[3 * i + 0] = m;
        in[3 * i + 1] = (m << 1) | (lf >> 63);
        in[3 * i + 2] = (m >> 1) | (rg << 63);
    }
    u64 s0a, c0a, s0b, c0b, s0c, c0c, c0d, s1a, c1a, c1b;
    FAD(in[0], in[1], in[2], s0a, c0a);
    FAD(in[3], in[4], in[5], s0b, c0b);
    FAD(in[6], in[7], in[8], s0c, c0c);
    FAD(s0a, s0b, s0c, P0, c0d);
    FAD(c0a, c0b, c0c, s1a, c1a);
    P1 = s1a ^ c0d;
    c1b = s1a & c0d;
    P2 = c1a ^ c1b;
    P3 = c1a & c1b;
}

// 192-bit seeded run-fill: o = union of maximal runs of f that intersect c.
// Carry trick: (f+c)&~f marks the bit above each seeded run; the bit-reversed
// add marks the bit below; MU - MD (borrow-in = reverse carry-out) paints
// [s-1, e] per seeded run; & f trims to [s, e]. Borrow ripple auto-handles
// runs touching bit 191. Verified: multi-seed runs, adjacent runs sharing a
// 1-bit gap (marker collision cancels), runs at both row edges.
__device__ __forceinline__ void runfill3(const u64 f0, const u64 f1, const u64 f2,
                                         u64 c0, u64 c1, u64 c2,
                                         u64& o0, u64& o1, u64& o2)
{
    c0 &= f0; c1 &= f1; c2 &= f2;
    // forward 192-bit add: markers above seeded runs
    u64 a0 = f0 + c0;  u64 k0 = (u64)(a0 < f0);
    u64 t1 = f1 + c1;  u64 k1 = (u64)(t1 < f1);
    u64 a1 = t1 + k0;  k1 |= (u64)(a1 < t1);
    u64 t2 = f2 + c2;
    u64 a2 = t2 + k1;
    const u64 mU0 = a0 & ~f0, mU1 = a1 & ~f1, mU2 = a2 & ~f2;
    // reversed add: markers below seeded runs
    const u64 rf0 = __brevll(f2), rf1 = __brevll(f1), rf2 = __brevll(f0);
    const u64 rc0 = __brevll(c2), rc1 = __brevll(c1), rc2 = __brevll(c0);
    u64 b0 = rf0 + rc0; u64 j0 = (u64)(b0 < rf0);
    u64 u1 = rf1 + rc1; u64 j1 = (u64)(u1 < rf1);
    u64 b1 = u1 + j0;   j1 |= (u64)(b1 < u1);
    u64 u2 = rf2 + rc2; u64 j2 = (u64)(u2 < rf2);
    u64 b2 = u2 + j1;   j2 |= (u64)(b2 < u2);
    const u64 mD0 = __brevll(b2 & ~rf2);
    const u64 mD1 = __brevll(b1 & ~rf1);
    const u64 mD2 = __brevll(b0 & ~rf0);
    // D = MU - MD - j2 (192-bit subtract; j2 = run-at-bit-0 seeded)
    u64 s0 = mU0 - mD0; u64 w0 = (u64)(mU0 < mD0);
    u64 d0 = s0 - j2;   w0 |= (u64)(s0 < j2);
    u64 s1 = mU1 - mD1; u64 w1 = (u64)(mU1 < mD1);
    u64 d1 = s1 - w0;   w1 |= (u64)(s1 < w0);
    u64 d2 = (mU2 - mD2) - w1;
    o0 = d0 & f0; o1 = d1 & f1; o2 = d2 & f2;
}

__global__ __launch_bounds__(NT) void cc_fused(
    const float* __restrict__ preds,
    const int* __restrict__ samples,
    double* __restrict__ acc)
{
    __shared__ u64 fgw[NWORDS];   // built via u16 nibble alias (zero repack)
    __shared__ u64 cmp[NWORDS];
    __shared__ unsigned wkey[NW];
    __shared__ double wsum[NW];
    __shared__ unsigned seedSh;
    __shared__ int cntSh;
    __shared__ short wlist[NWORDS];

    // XCD-locality mapping: the 3 class-tasks of one (b,s) are 160 apart;
    // 160 % 8 == 0 -> same XCD -> samples L2 reuse.
    const int blk = blockIdx.x;
    const int c = 1 + blk / NPAIR;
    const int pair = blk % NPAIR;
    const int b = pair / SS;

    const int tid  = threadIdx.x;
    const int lane = tid & 63;
    const int wv   = tid >> 6;

    const int* __restrict__ smp  = samples + (size_t)pair * NPIX;
    const float* __restrict__ pp = preds + ((size_t)b * CLSN + c) * NPIX;

    if (tid == 0) cntSh = 0;

    float facc = 0.0f;

    // ---- Phase A: int4/float4 loads; 16-px mask nibble -> LDS u16 alias.
    // Fused dense term: -sum_{v==c} log(p + 1e-8).
    {
        u16* nib = (u16*)fgw;
        for (int sc = 0; sc < 9; ++sc) {
            const int ci = sc * NT + tid;
            const int px = ci << 4;
            const int4 v0 = *(const int4*)(smp + px);
            const int4 v1 = *(const int4*)(smp + px + 4);
            const int4 v2 = *(const int4*)(smp + px + 8);
            const int4 v3 = *(const int4*)(smp + px + 12);
            const float4 q0 = *(const float4*)(pp + px);
            const float4 q1 = *(const float4*)(pp + px + 4);
            const float4 q2 = *(const float4*)(pp + px + 8);
            const float4 q3 = *(const float4*)(pp + px + 12);
            unsigned m = 0u;
#define ACC1(vv, qq, sh)                                              \
            {                                                          \
                const bool hit_ = ((vv) == c);                         \
                m |= ((unsigned)hit_) << (sh);                         \
                facc -= hit_ ? __logf((qq) + 1e-8f) : 0.0f;            \
            }
            ACC1(v0.x, q0.x, 0)  ACC1(v0.y, q0.y, 1)
            ACC1(v0.z, q0.z, 2)  ACC1(v0.w, q0.w, 3)
            ACC1(v1.x, q1.x, 4)  ACC1(v1.y, q1.y, 5)
            ACC1(v1.z, q1.z, 6)  ACC1(v1.w, q1.w, 7)
            ACC1(v2.x, q2.x, 8)  ACC1(v2.y, q2.y, 9)
            ACC1(v2.z, q2.z, 10) ACC1(v2.w, q2.w, 11)
            ACC1(v3.x, q3.x, 12) ACC1(v3.y, q3.y, 13)
            ACC1(v3.z, q3.z, 14) ACC1(v3.w, q3.w, 15)
#undef ACC1
            nib[ci] = (u16)m;
        }
    }
    __syncthreads();

    // ---- Phase B: bit-sliced neighbor counts -> argmax seed (first-max tie-break) ----
    {
        unsigned bestkey = 0u;
        for (int k = tid; k < NWORDS; k += NT) {
            u64 P0, P1, P2, P3, mid;
            plane9(fgw, k, P0, P1, P2, P3, mid);
            if (mid) {
                u64 cand = mid, t;
                unsigned v = 0;
                t = cand & P3; if (t) { cand = t; v |= 8u; }
                t = cand & P2; if (t) { cand = t; v |= 4u; }
                t = cand & P1; if (t) { cand = t; v |= 2u; }
                t = cand & P0; if (t) { cand = t; v |= 1u; }
                unsigned pix = ((unsigned)k << 6) + (unsigned)(__ffsll(cand) - 1);
                unsigned key = (v << 16) | (36863u - pix);
                if (key > bestkey) bestkey = key;
            }
        }
#pragma unroll
        for (int off = 32; off > 0; off >>= 1) {
            unsigned o = (unsigned)__shfl_xor((int)bestkey, off, 64);
            if (o > bestkey) bestkey = o;
        }
        if (lane == 0) wkey[wv] = bestkey;
    }
    __syncthreads();
    if (tid == 0) {
        unsigned kk = wkey[0];
        if (wkey[1] > kk) kk = wkey[1];
        if (wkey[2] > kk) kk = wkey[2];
        if (wkey[3] > kk) kk = wkey[3];
        seedSh = 36863u - (kk & 0xFFFFu);
    }
    __syncthreads();

    // ---- Phase C: register flood fill on wave 0, full-run horizontal jumps ----
    // Lane l owns rows 3l..3l+2. Per row-step: seeds = hsmear(vertical nbrs)
    // | cur, then 192-bit run-fill -> whole horizontal runs in one step.
    // Iterations are bounded by the component's VERTICAL extent only.
    if (wv == 0) {
        const unsigned seed = seedSh;
        u64 f[3][3], cc[3][3];
        const int rbase = 3 * lane;
#pragma unroll
        for (int j = 0; j < 3; ++j)
#pragma unroll
            for (int w = 0; w < 3; ++w) {
                f[j][w] = fgw[(rbase + j) * WPR + w];
                cc[j][w] = 0ULL;
            }
        {
            const int sr = (int)(seed / WW), sc_ = (int)(seed % WW);
            const int sw = sc_ >> 6, sb = sc_ & 63;
            if (sr / 3 == lane) {
                const int jj = sr % 3;
                u64 bit = (1ULL << sb);
#pragma unroll
                for (int j = 0; j < 3; ++j)
#pragma unroll
                    for (int w = 0; w < 3; ++w)
                        if (j == jj && w == sw) cc[j][w] = bit & f[j][w];
            }
            // pre-fill the seed's own run (saves one iteration)
            if (sr / 3 == lane) {
                const int jj = sr % 3;
                u64 n0, n1, n2;
                runfill3(f[jj][0], f[jj][1], f[jj][2],
                         cc[jj][0], cc[jj][1], cc[jj][2], n0, n1, n2);
                cc[jj][0] = n0; cc[jj][1] = n1; cc[jj][2] = n2;
            }
        }
        for (;;) {
            u64 bA0 = __shfl_up(cc[2][0], 1, 64);
            u64 bA1 = __shfl_up(cc[2][1], 1, 64);
            u64 bA2 = __shfl_up(cc[2][2], 1, 64);
            u64 tB0 = __shfl_down(cc[0][0], 1, 64);
            u64 tB1 = __shfl_down(cc[0][1], 1, 64);
            u64 tB2 = __shfl_down(cc[0][2], 1, 64);
            if (lane == 0)  { bA0 = bA1 = bA2 = 0ULL; }
            if (lane == 63) { tB0 = tB1 = tB2 = 0ULL; }

            u64 d = 0ULL;
            // row-step: seeds = hsmear(up|dn) | cur; run-fill whole runs.
#define RSTEP(J, T0, T1, T2, B0, B1, B2)                                       \
            {                                                                  \
                u64 v0 = (T0) | (B0), v1 = (T1) | (B1), v2 = (T2) | (B2);      \
                u64 e0, e1, e2;                                                \
                SMEAR3(v0, v1, v2, e0, e1, e2);                                \
                e0 |= cc[J][0]; e1 |= cc[J][1]; e2 |= cc[J][2];                \
                u64 n0, n1, n2;                                                \
                runfill3(f[J][0], f[J][1], f[J][2], e0, e1, e2, n0, n1, n2);   \
                d |= (n0 & ~cc[J][0]) | (n1 & ~cc[J][1]) | (n2 & ~cc[J][2]);   \
                cc[J][0] = n0; cc[J][1] = n1; cc[J][2] = n2;                   \
            }
            // Gauss-Seidel down
            RSTEP(0, bA0, bA1, bA2, cc[1][0], cc[1][1], cc[1][2])
            RSTEP(1, cc[0][0], cc[0][1], cc[0][2], cc[2][0], cc[2][1], cc[2][2])
            RSTEP(2, cc[1][0], cc[1][1], cc[1][2], tB0, tB1, tB2)
            // Gauss-Seidel up
            RSTEP(1, cc[0][0], cc[0][1], cc[0][2], cc[2][0], cc[2][1], cc[2][2])
            RSTEP(0, bA0, bA1, bA2, cc[1][0], cc[1][1], cc[1][2])
#undef RSTEP
            if (!__any(d != 0ULL)) break;
        }
#pragma unroll
        for (int j = 0; j < 3; ++j)
#pragma unroll
            for (int w = 0; w < 3; ++w)
                cmp[(rbase + j) * WPR + w] = cc[j][w];
    }
    __syncthreads();

    // ---- Phase D: compact nonempty comp words, split across waves,
    //      software-pipelined preds gather. facc += (cnt/9 + 1) * log(p).
    for (int k = tid; k < NWORDS; k += NT)
        if (cmp[k] != 0ULL) { int idx = atomicAdd(&cntSh, 1); wlist[idx] = (short)k; }
    __syncthreads();
    {
        const int n = cntSh;
        int i = wv;
        int kc = (i < n) ? (int)wlist[i] : -1;
        float pc = 0.0f;
        if (kc >= 0) pc = pp[(kc << 6) + lane];
        while (kc >= 0) {
            const int i2 = i + NW;
            const int k2 = (i2 < n) ? (int)wlist[i2] : -1;
            float p2 = 0.0f;
            if (k2 >= 0) p2 = pp[(k2 << 6) + lane];   // next load in flight
            u64 P0, P1, P2, P3, mid;
            plane9(cmp, kc, P0, P1, P2, P3, mid);
            if ((mid >> lane) & 1ULL) {
                int ct = (int)((P0 >> lane) & 1ULL)
                       | ((int)((P1 >> lane) & 1ULL) << 1)
                       | ((int)((P2 >> lane) & 1ULL) << 2)
                       | ((int)((P3 >> lane) & 1ULL) << 3);
                facc += ((float)ct * (1.0f / 9.0f) + 1.0f) * __logf(pc + 1e-8f);
            }
            i = i2; kc = k2; pc = p2;
        }
    }

    // ---- Reduce ----
#pragma unroll
    for (int off = 32; off > 0; off >>= 1)
        facc += __shfl_xor(facc, off, 64);
    if (lane == 0) wsum[wv] = (double)facc;
    __syncthreads();
    if (tid == 0)
        atomicAdd(acc, wsum[0] + wsum[1] + wsum[2] + wsum[3]);
}

__global__ void finalize_kernel(const double* __restrict__ acc, float* __restrict__ out)
{
    if (threadIdx.x == 0 && blockIdx.x == 0)
        out[0] = (float)(-acc[0] / (double)((long long)BB * SS * NPIX));
}

extern "C" void kernel_launch(void* const* d_in, const int* in_sizes, int n_in,
                              void* d_out, int out_size, void* d_ws, size_t ws_size,
                              hipStream_t stream)
{
    const float* preds   = (const float*)d_in[0];
    const int*   samples = (const int*)d_in[1];
    double* acc = (double*)d_ws;

    hipMemsetAsync(acc, 0, sizeof(double), stream);
    hipLaunchKernelGGL(cc_fused, dim3(NTASK), dim3(NT), 0, stream,
                       preds, samples, acc);
    hipLaunchKernelGGL(finalize_kernel, dim3(1), dim3(64), 0, stream,
                       acc, (float*)d_out);
}